// Round 5
// baseline (107.957 us; speedup 1.0000x reference)
//
#include <hip/hip_runtime.h>

#define N_ 256
#define E_ 32640

typedef __bf16 bf16x8 __attribute__((ext_vector_type(8)));
typedef float f32x4 __attribute__((ext_vector_type(4)));

__device__ __forceinline__ unsigned short cvt1(float f) {
  return __builtin_bit_cast(unsigned short, (__bf16)f);
}

// Swizzled LDS helpers: row-major bf16, byte ^= (row&7)<<4
__device__ __forceinline__ bf16x8 ldfrag(const unsigned short* base, int row, int kbyte, int rowbytes) {
  int byte = (row * rowbytes + kbyte) ^ ((row & 7) << 4);
  return *reinterpret_cast<const bf16x8*>(reinterpret_cast<const char*>(base) + byte);
}

__device__ __forceinline__ void st2(unsigned short* base, int row, int colbyte, int rowbytes, unsigned short v) {
  int byte = (row * rowbytes + colbyte) ^ ((row & 7) << 4);
  *reinterpret_cast<unsigned short*>(reinterpret_cast<char*>(base) + byte) = v;
}

// Write one edge's 3 types into the 3 sA planes; shared vaddr + imm offsets.
__device__ __forceinline__ void stA3(unsigned short* sA0, int lr, int cb, float4 v) {
  int byte = (lr * 512 + cb) ^ ((lr & 7) << 4);
  char* p = reinterpret_cast<char*>(sA0) + byte;
  *reinterpret_cast<unsigned short*>(p)         = cvt1(v.y);
  *reinterpret_cast<unsigned short*>(p + 16384) = cvt1(v.z);
  *reinterpret_cast<unsigned short*>(p + 32768) = cvt1(v.w);
}

__device__ __forceinline__ bf16x8 pack8(float4 lo, float4 hi) {
  bf16x8 r;
  r[0] = (__bf16)lo.x; r[1] = (__bf16)lo.y; r[2] = (__bf16)lo.z; r[3] = (__bf16)lo.w;
  r[4] = (__bf16)hi.x; r[5] = (__bf16)hi.y; r[6] = (__bf16)hi.z; r[7] = (__bf16)hi.w;
  return r;
}

// One block = one (batch, 32-row chunk). 512 threads = 8 waves.
__global__ __launch_bounds__(512, 4) void chunk_kernel(
    const float* __restrict__ se_g,
    const float* __restrict__ w1,  const float* __restrict__ b1,
    const float* __restrict__ w2,  const float* __restrict__ b2,
    const float* __restrict__ wo1, const float* __restrict__ bo1,
    const float* __restrict__ wo2, const float* __restrict__ bo2,
    float* __restrict__ ws)
{
  __shared__ __align__(16) unsigned short sA[3 * 32 * N_];   // 3 planes of [32][256], 48 KB
  __shared__ __align__(16) unsigned short sH3[3 * 32 * 128]; // 3 x [32][128], 24 KB
  __shared__ float sAccW[8][64];

  const int tid = threadIdx.x;
  const int i   = blockIdx.x;
  // XCD-aware decode: all 8 chunks of a batch share i&7 -> same XCD
  const int batch = (i & 7) * 32 + ((i >> 3) & 31);
  const int chunk = i >> 8;
  const int r0    = chunk * 32;

  const int w   = tid >> 6;   // wave 0..7
  const int l   = tid & 63;
  const int l15 = l & 15;
  const int lk  = l >> 4;     // 0..3
  const int kb0 = lk * 16;

  const int c1 = w;           // GEMM1 col-tile (of 8); row-tiles 0,1
  const int r2 = w >> 2;      // GEMM2/head row-tile (of 2)
  const int c2 = w & 3;       // GEMM2/head col-tile (of 4)

  // sAccW is only partially written per wave (each wave covers 16 of 64 cols):
  // MUST zero-init before use. Ordered against writers by barrier #1..#4.
  reinterpret_cast<float*>(sAccW)[tid] = 0.f;

  // ---- W1/W2 B-fragments -> registers ----
  bf16x8 W1f[8];
  {
    const float* p = w1 + (c1 * 16 + l15) * 256 + lk * 8;
    #pragma unroll
    for (int ks = 0; ks < 8; ++ks) {
      float4 lo = *reinterpret_cast<const float4*>(p + ks * 32);
      float4 hi = *reinterpret_cast<const float4*>(p + ks * 32 + 4);
      W1f[ks] = pack8(lo, hi);
    }
  }
  bf16x8 W2f[4];
  {
    const float* p = w2 + (c2 * 16 + l15) * 128 + lk * 8;
    #pragma unroll
    for (int ks = 0; ks < 4; ++ks) {
      float4 lo = *reinterpret_cast<const float4*>(p + ks * 32);
      float4 hi = *reinterpret_cast<const float4*>(p + ks * 32 + 4);
      W2f[ks] = pack8(lo, hi);
    }
  }

  const float4* seB = reinterpret_cast<const float4*>(se_g) + (size_t)batch * E_;

  // ---- (a) upper triangle: contiguous edge span, depth-2 pipelined loads ----
  {
    const int span0 = (r0 * (511 - r0)) >> 1;                       // ubase(r0)
    const int S     = (((r0 + 32) * (479 - r0)) >> 1) - span0;      // ubase(r0+32)-ubase(r0)
    int t = tid;
    float4 p0 = {}, p1 = {};
    if (t < S)       p0 = seB[span0 + t];
    if (t + 512 < S) p1 = seB[span0 + t + 512];
    for (; t < S; t += 512) {
      float4 v = p0;
      p0 = p1;
      if (t + 1024 < S) p1 = seB[span0 + t + 1024];
      int g = span0 + t;                                  // global edge index
      // row gi: largest gi with gi*(511-gi)/2 <= g (inverse triangular)
      float disc = (float)(261121 - 8 * g);
      int gi = (int)((511.0f - sqrtf(disc)) * 0.5f);
      while (gi * (511 - gi) > 2 * g) --gi;
      while ((gi + 1) * (510 - gi) <= 2 * g) ++gi;
      int j = g - ((gi * (511 - gi)) >> 1) + gi + 1;
      stA3(sA, gi - r0, j * 2, v);
    }
  }
  // ---- (b) lower triangle via column strips, batched x4 prefetch ----
  {
    const int sub = tid >> 5, l32 = tid & 31;
    const int K = (r0 + 31 + 15) >> 4;   // ceil((r0+31)/16)
    for (int k0 = 0; k0 < K; k0 += 4) {
      float4 v[4]; int lr[4], cb[4]; bool ok[4];
      #pragma unroll
      for (int kk = 0; kk < 4; ++kk) {
        int j   = sub + ((k0 + kk) << 4);
        int i0  = (j + 1 > r0) ? (j + 1) : r0;
        int cnt = r0 + 32 - i0;
        int ii  = i0 + l32;
        bool val = (j < r0 + 31) && (l32 < cnt);
        int u = j * 255 - ((j * (j - 1)) >> 1) + (ii - j - 1);
        ok[kk] = val; lr[kk] = ii - r0; cb[kk] = j * 2;
        v[kk] = seB[val ? u : 0];
      }
      #pragma unroll
      for (int kk = 0; kk < 4; ++kk)
        if (ok[kk]) stA3(sA, lr[kk], cb[kk], v[kk]);
    }
  }
  // diagonal = 0
  if (tid < 32) {
    int byte = (tid * 512 + (r0 + tid) * 2) ^ ((tid & 7) << 4);
    char* p = reinterpret_cast<char*>(sA) + byte;
    *reinterpret_cast<unsigned short*>(p)         = 0;
    *reinterpret_cast<unsigned short*>(p + 16384) = 0;
    *reinterpret_cast<unsigned short*>(p + 32768) = 0;
  }
  __syncthreads();   // #1: A staged (+ sAccW init)

  // ---- GEMM1 for all 3 e: H3[e][32][128] = relu(A_e @ W1^T + b1) ----
  {
    const float bias = b1[c1 * 16 + l15];
    #pragma unroll
    for (int e = 0; e < 3; ++e) {
      f32x4 acc0 = {0,0,0,0}, acc1 = {0,0,0,0};
      const unsigned short* sAe = sA + e * (32 * N_);
      #pragma unroll
      for (int ks = 0; ks < 8; ++ks) {
        int kb = ks * 64 + kb0;
        bf16x8 a0 = ldfrag(sAe, l15,      kb, 512);
        bf16x8 a1 = ldfrag(sAe, 16 + l15, kb, 512);
        acc0 = __builtin_amdgcn_mfma_f32_16x16x32_bf16(a0, W1f[ks], acc0, 0, 0, 0);
        acc1 = __builtin_amdgcn_mfma_f32_16x16x32_bf16(a1, W1f[ks], acc1, 0, 0, 0);
      }
      unsigned short* sHe = sH3 + e * (32 * 128);
      int cc = c1 * 16 + l15;
      #pragma unroll
      for (int r = 0; r < 4; ++r) {
        st2(sHe, lk * 4 + r,      cc * 2, 256, cvt1(fmaxf(acc0[r] + bias, 0.f)));
        st2(sHe, 16 + lk * 4 + r, cc * 2, 256, cvt1(fmaxf(acc1[r] + bias, 0.f)));
      }
    }
  }
  __syncthreads();   // #2: H ready

  // ---- GEMM2 all e + weighted accumulate; X-write into dead sA ----
  unsigned short* sX = sA;               // [32][64] rowbytes 128, bytes [0,4096)
  unsigned short* sP = sA + 2048;        // bytes [4096,8192)
  bf16x8 WO1f[2], WO2f[2];
  {
    f32x4 outAcc = {0,0,0,0};
    const float bias = b2[c2 * 16 + l15];
    int arow = r2 * 16 + l15;
    #pragma unroll
    for (int e = 0; e < 3; ++e) {
      f32x4 acc = {0,0,0,0};
      const unsigned short* sHe = sH3 + e * (32 * 128);
      #pragma unroll
      for (int ks = 0; ks < 4; ++ks) {
        bf16x8 a = ldfrag(sHe, arow, ks * 64 + kb0, 256);
        acc = __builtin_amdgcn_mfma_f32_16x16x32_bf16(a, W2f[ks], acc, 0, 0, 0);
      }
      float wte = 0.2f * (float)(e + 1);
      #pragma unroll
      for (int r = 0; r < 4; ++r)
        outAcc[r] += wte * fmaxf(acc[r] + bias, 0.f);
    }
    // head B-frags (L2-hot), issued here to overlap barrier
    {
      const float* p1 = wo1 + (c2 * 16 + l15) * 64 + lk * 8;
      const float* p2 = wo2 + (c2 * 16 + l15) * 64 + lk * 8;
      #pragma unroll
      for (int ks = 0; ks < 2; ++ks) {
        WO1f[ks] = pack8(*reinterpret_cast<const float4*>(p1 + ks * 32),
                         *reinterpret_cast<const float4*>(p1 + ks * 32 + 4));
        WO2f[ks] = pack8(*reinterpret_cast<const float4*>(p2 + ks * 32),
                         *reinterpret_cast<const float4*>(p2 + ks * 32 + 4));
      }
    }
    int col = c2 * 16 + l15;
    #pragma unroll
    for (int r = 0; r < 4; ++r)
      st2(sX, r2 * 16 + lk * 4 + r, col * 2, 128, cvt1(outAcc[r]));
  }
  __syncthreads();   // #3: X ready

  // ---- head GEMM 1: P = relu(X @ WO1^T + bo1) ----
  {
    const float bias = bo1[c2 * 16 + l15];
    f32x4 acc = {0,0,0,0};
    int arow = r2 * 16 + l15;
    #pragma unroll
    for (int ks = 0; ks < 2; ++ks) {
      bf16x8 a = ldfrag(sX, arow, ks * 64 + kb0, 128);
      acc = __builtin_amdgcn_mfma_f32_16x16x32_bf16(a, WO1f[ks], acc, 0, 0, 0);
    }
    #pragma unroll
    for (int r = 0; r < 4; ++r)
      st2(sP, r2 * 16 + lk * 4 + r, (c2 * 16 + l15) * 2, 128, cvt1(fmaxf(acc[r] + bias, 0.f)));
  }
  __syncthreads();   // #4: P ready

  // ---- head GEMM 2 + row-sum reduce ----
  {
    const float bias = bo2[c2 * 16 + l15];
    f32x4 acc = {0,0,0,0};
    int arow = r2 * 16 + l15;
    #pragma unroll
    for (int ks = 0; ks < 2; ++ks) {
      bf16x8 a = ldfrag(sP, arow, ks * 64 + kb0, 128);
      acc = __builtin_amdgcn_mfma_f32_16x16x32_bf16(a, WO2f[ks], acc, 0, 0, 0);
    }
    float s = 0.f;
    #pragma unroll
    for (int r = 0; r < 4; ++r) s += fmaxf(acc[r] + bias, 0.f);
    s += __shfl_xor(s, 16);
    s += __shfl_xor(s, 32);
    if (lk == 0) sAccW[w][c2 * 16 + l15] = s;
  }
  __syncthreads();   // #5

  if (tid < 64) {
    float s = 0.f;
    #pragma unroll
    for (int ww = 0; ww < 8; ++ww) s += sAccW[ww][tid];
    ws[((size_t)batch * 8 + chunk) * 64 + tid] = s;
  }
}

// 32 blocks x 512: 8 batches per block; sum chunk partials, mean, project 64->2.
__global__ __launch_bounds__(512) void finish_kernel(
    const float* __restrict__ ws,
    const float* __restrict__ wo3, const float* __restrict__ bo3,
    float* __restrict__ out)
{
  int b = blockIdx.x * 8 + (threadIdx.x >> 6);
  int l = threadIdx.x & 63;
  float s = 0.f;
  #pragma unroll
  for (int c = 0; c < 8; ++c) s += ws[((size_t)b * 8 + c) * 64 + l];
  s *= (1.0f / 256.0f);
  float v0 = s * wo3[l];
  float v1 = s * wo3[64 + l];
  #pragma unroll
  for (int off = 32; off > 0; off >>= 1) {
    v0 += __shfl_down(v0, off);
    v1 += __shfl_down(v1, off);
  }
  if (l == 0) {
    out[b * 2 + 0] = v0 + bo3[0];
    out[b * 2 + 1] = v1 + bo3[1];
  }
}

extern "C" void kernel_launch(void* const* d_in, const int* in_sizes, int n_in,
                              void* d_out, int out_size, void* d_ws, size_t ws_size,
                              hipStream_t stream) {
  (void)in_sizes; (void)n_in; (void)ws_size; (void)out_size;
  const float* se  = (const float*)d_in[1];   // d_in[0] = `inputs` — shape-only, never read
  const float* w1  = (const float*)d_in[2];
  const float* b1  = (const float*)d_in[3];
  const float* w2  = (const float*)d_in[4];
  const float* b2  = (const float*)d_in[5];
  const float* wo1 = (const float*)d_in[6];
  const float* bo1 = (const float*)d_in[7];
  const float* wo2 = (const float*)d_in[8];
  const float* bo2 = (const float*)d_in[9];
  const float* wo3 = (const float*)d_in[10];
  const float* bo3 = (const float*)d_in[11];
  float* ws = (float*)d_ws;                   // 2048 * 64 floats = 512 KB
  chunk_kernel<<<dim3(2048), dim3(512), 0, stream>>>(
      se, w1, b1, w2, b2, wo1, bo1, wo2, bo2, ws);
  finish_kernel<<<dim3(32), dim3(512), 0, stream>>>(ws, wo3, bo3, (float*)d_out);
}

// Round 6
// 103.785 us; speedup vs baseline: 1.0402x; 1.0402x over previous
//
#include <hip/hip_runtime.h>

#define E_ 32640

typedef __bf16 bf16x8 __attribute__((ext_vector_type(8)));
typedef float f32x4 __attribute__((ext_vector_type(4)));

__device__ __forceinline__ unsigned short cvt1(float f) {
  return __builtin_bit_cast(unsigned short, (__bf16)f);
}

// Swizzled LDS helpers: row-major bf16, byte ^= (row&7)<<4
__device__ __forceinline__ bf16x8 ldfrag(const unsigned short* base, int row, int kbyte, int rowbytes) {
  int byte = (row * rowbytes + kbyte) ^ ((row & 7) << 4);
  return *reinterpret_cast<const bf16x8*>(reinterpret_cast<const char*>(base) + byte);
}
__device__ __forceinline__ void st2(unsigned short* base, int row, int colbyte, int rowbytes, unsigned short v) {
  int byte = (row * rowbytes + colbyte) ^ ((row & 7) << 4);
  *reinterpret_cast<unsigned short*>(reinterpret_cast<char*>(base) + byte) = v;
}
// Write one edge's 3 types into the 3 sA planes ([16][256] each, +8192 B apart)
__device__ __forceinline__ void stA3(unsigned short* sA0, int lr, int cb, float4 v) {
  int byte = (lr * 512 + cb) ^ ((lr & 7) << 4);
  char* p = reinterpret_cast<char*>(sA0) + byte;
  *reinterpret_cast<unsigned short*>(p)         = cvt1(v.y);
  *reinterpret_cast<unsigned short*>(p + 8192)  = cvt1(v.z);
  *reinterpret_cast<unsigned short*>(p + 16384) = cvt1(v.w);
}
__device__ __forceinline__ bf16x8 pack8(float4 lo, float4 hi) {
  bf16x8 r;
  r[0] = (__bf16)lo.x; r[1] = (__bf16)lo.y; r[2] = (__bf16)lo.z; r[3] = (__bf16)lo.w;
  r[4] = (__bf16)hi.x; r[5] = (__bf16)hi.y; r[6] = (__bf16)hi.z; r[7] = (__bf16)hi.w;
  return r;
}

__device__ __forceinline__ int ubase(int i) { return (i * (511 - i)) >> 1; }

// g (global upper-edge index) -> (row gi, col j)
__device__ __forceinline__ void decode_g(int g, int& gi, int& j) {
  float disc = (float)(261121 - 8 * g);
  int t = (int)((511.0f - sqrtf(disc)) * 0.5f);
  while (t * (511 - t) > 2 * g) --t;
  while ((t + 1) * (510 - t) <= 2 * g) ++t;
  gi = t;
  j = g - ((t * (511 - t)) >> 1) + t + 1;
}

// Lower triangle of rows [r0, r0+16): column strips j = 0..r0+14, 16 lanes each.
__device__ __forceinline__ void stage_lower(const float4* seB, unsigned short* sA,
                                            int r0, int glane, int ngroups) {
  const int sub = glane >> 4, l16 = glane & 15;
  const int nStrips = r0 + 15;
  for (int j0 = sub; j0 < nStrips; j0 += ngroups * 4) {
    float4 v[4]; int lr[4], cb[4]; bool ok[4];
    #pragma unroll
    for (int kk = 0; kk < 4; ++kk) {
      int j  = j0 + kk * ngroups;
      int i0 = (j + 1 > r0) ? (j + 1) : r0;
      int cnt = r0 + 16 - i0;
      int ii = i0 + l16;
      bool val = (j < nStrips) && (l16 < cnt);
      int u = j * 255 - ((j * (j - 1)) >> 1) + (ii - j - 1);
      ok[kk] = val; lr[kk] = ii - r0; cb[kk] = j * 2;
      v[kk] = seB[val ? u : 0];
    }
    #pragma unroll
    for (int kk = 0; kk < 4; ++kk)
      if (ok[kk]) stA3(sA, lr[kk], cb[kk], v[kk]);
  }
}

// Upper span of rows [r0, r0+16), synchronous depth-2 pipeline (prologue only)
__device__ __forceinline__ void stage_upper_sync(const float4* seB, unsigned short* sA,
                                                 int r0, int tid) {
  const int s0 = ubase(r0);
  const int S  = ubase(r0 + 16) - s0;
  int t = tid;
  float4 p0 = {}, p1 = {};
  if (t < S)       p0 = seB[s0 + t];
  if (t + 512 < S) p1 = seB[s0 + t + 512];
  for (; t < S; t += 512) {
    float4 v = p0; p0 = p1;
    if (t + 1024 < S) p1 = seB[s0 + t + 1024];
    int gi, j; decode_g(s0 + t, gi, j);
    stA3(sA, gi - r0, j * 2, v);
  }
}

// One block = (batch, half): 8 chunks of 16 rows, software-pipelined.
__global__ __launch_bounds__(512, 2) void chunk_kernel(
    const float* __restrict__ se_g,
    const float* __restrict__ w1,  const float* __restrict__ b1,
    const float* __restrict__ w2,  const float* __restrict__ b2,
    const float* __restrict__ wo1, const float* __restrict__ bo1,
    const float* __restrict__ wo2, const float* __restrict__ bo2,
    float* __restrict__ ws)
{
  __shared__ __align__(16) unsigned short sA[3 * 16 * 256];   // 24 KB, rowbytes 512
  __shared__ __align__(16) unsigned short sH3[3 * 16 * 128];  // 12 KB, rowbytes 256
  __shared__ __align__(16) unsigned short sXP[2 * 16 * 64];   // 4 KB: X@0, P@+2048B
  __shared__ float sAccC[64];

  const int tid = threadIdx.x;
  const int i   = blockIdx.x;
  // blocks i and i+256 share (i&7) -> same XCD; same batch, halves 0/1
  const int half  = i >> 8;
  const int within = i & 255;
  const int batch = (within & 7) * 32 + (within >> 3);
  const int cbase = half * 8;                 // global 16-row chunk base

  const int w   = tid >> 6;   // wave 0..7
  const int l   = tid & 63;
  const int l15 = l & 15;
  const int lk  = l >> 4;
  const int kb0 = lk * 16;

  const int c1 = w;            // GEMM1 col-tile (of 8)
  const int c2 = w & 3;        // GEMM2/head col-tile (of 4)
  const bool isHead = (w < 4);

  if (tid < 64) sAccC[tid] = 0.f;

  // ---- persistent weight fragments ----
  bf16x8 W1f[8];
  {
    const float* p = w1 + (c1 * 16 + l15) * 256 + lk * 8;
    #pragma unroll
    for (int ks = 0; ks < 8; ++ks)
      W1f[ks] = pack8(*reinterpret_cast<const float4*>(p + ks * 32),
                      *reinterpret_cast<const float4*>(p + ks * 32 + 4));
  }
  bf16x8 W2f[4];
  {
    const float* p = w2 + (c2 * 16 + l15) * 128 + lk * 8;
    #pragma unroll
    for (int ks = 0; ks < 4; ++ks)
      W2f[ks] = pack8(*reinterpret_cast<const float4*>(p + ks * 32),
                      *reinterpret_cast<const float4*>(p + ks * 32 + 4));
  }
  const float b1v  = b1[c1 * 16 + l15];
  const float b2v  = b2[c2 * 16 + l15];
  const float bo1v = bo1[c2 * 16 + l15];
  const float bo2v = bo2[c2 * 16 + l15];

  const float4* seB = reinterpret_cast<const float4*>(se_g) + (size_t)batch * E_;
  unsigned short* sX = sXP;
  unsigned short* sP = sXP + 16 * 64;

  // ---- prologue: stage chunk cbase (cold) ----
  {
    int r0 = cbase * 16;
    stage_upper_sync(seB, sA, r0, tid);
    stage_lower(seB, sA, r0, tid, 32);
    if (tid < 16) {  // diagonal = 0
      int byte = (tid * 512 + (r0 + tid) * 2) ^ ((tid & 7) << 4);
      char* p = reinterpret_cast<char*>(sA) + byte;
      *reinterpret_cast<unsigned short*>(p)         = 0;
      *reinterpret_cast<unsigned short*>(p + 8192)  = 0;
      *reinterpret_cast<unsigned short*>(p + 16384) = 0;
    }
  }
  __syncthreads();   // bar0: chunk 0 staged, sAccC init

  for (int cc = 0; cc < 8; ++cc) {
    const int r0 = (cbase + cc) * 16;
    const bool more = (cc < 7);
    const int nr0 = r0 + 16;

    // ---- Phase A: issue next-chunk upper prefetch (8 deep, covers span<=3704) ----
    float4 pf[8];
    int s0 = 0, S = 0;
    if (more) {
      s0 = ubase(nr0);
      S  = ubase(nr0 + 16) - s0;
      #pragma unroll
      for (int k = 0; k < 8; ++k) {
        int t = tid + k * 512;
        pf[k] = seB[s0 + (t < S ? t : 0)];
      }
    }

    // ---- Phase B: GEMM1 (all waves): H3[e] = relu(A_e @ W1^T + b1) ----
    {
      const int ccol = c1 * 16 + l15;
      #pragma unroll
      for (int e = 0; e < 3; ++e) {
        f32x4 acc = {0, 0, 0, 0};
        const unsigned short* sAe = sA + e * 4096;
        #pragma unroll
        for (int ks = 0; ks < 8; ++ks)
          acc = __builtin_amdgcn_mfma_f32_16x16x32_bf16(
              ldfrag(sAe, l15, ks * 64 + kb0, 512), W1f[ks], acc, 0, 0, 0);
        unsigned short* sHe = sH3 + e * 2048;
        #pragma unroll
        for (int r = 0; r < 4; ++r)
          st2(sHe, lk * 4 + r, ccol * 2, 256, cvt1(fmaxf(acc[r] + b1v, 0.f)));
      }
    }
    __syncthreads();   // bar1: H ready; sA dead -> staging may write

    // ---- Phase C ----
    // (1) all waves: decode + LDS-write the prefetched upper edges of chunk cc+1
    if (more) {
      #pragma unroll
      for (int k = 0; k < 8; ++k) {
        int t = tid + k * 512;
        if (t < S) {
          int gi, j; decode_g(s0 + t, gi, j);
          stA3(sA, gi - nr0, j * 2, pf[k]);
        }
      }
      if (tid < 16) {  // next diagonal = 0
        int byte = (tid * 512 + (nr0 + tid) * 2) ^ ((tid & 7) << 4);
        char* p = reinterpret_cast<char*>(sA) + byte;
        *reinterpret_cast<unsigned short*>(p)         = 0;
        *reinterpret_cast<unsigned short*>(p + 8192)  = 0;
        *reinterpret_cast<unsigned short*>(p + 16384) = 0;
      }
    }
    // (2) split: waves 0-3 GEMM2 + X; waves 4-7 lower strips of chunk cc+1
    bf16x8 WO1f[2], WO2f[2];
    if (isHead) {
      const float* q1 = wo1 + (c2 * 16 + l15) * 64 + lk * 8;
      const float* q2 = wo2 + (c2 * 16 + l15) * 64 + lk * 8;
      float4 wa0 = *reinterpret_cast<const float4*>(q1);
      float4 wa1 = *reinterpret_cast<const float4*>(q1 + 4);
      float4 wa2 = *reinterpret_cast<const float4*>(q1 + 32);
      float4 wa3 = *reinterpret_cast<const float4*>(q1 + 36);
      float4 wb0 = *reinterpret_cast<const float4*>(q2);
      float4 wb1 = *reinterpret_cast<const float4*>(q2 + 4);
      float4 wb2 = *reinterpret_cast<const float4*>(q2 + 32);
      float4 wb3 = *reinterpret_cast<const float4*>(q2 + 36);
      f32x4 outAcc = {0, 0, 0, 0};
      #pragma unroll
      for (int e = 0; e < 3; ++e) {
        f32x4 acc = {0, 0, 0, 0};
        const unsigned short* sHe = sH3 + e * 2048;
        #pragma unroll
        for (int ks = 0; ks < 4; ++ks)
          acc = __builtin_amdgcn_mfma_f32_16x16x32_bf16(
              ldfrag(sHe, l15, ks * 64 + kb0, 256), W2f[ks], acc, 0, 0, 0);
        float wte = 0.2f * (float)(e + 1);
        #pragma unroll
        for (int r = 0; r < 4; ++r)
          outAcc[r] += wte * fmaxf(acc[r] + b2v, 0.f);
      }
      WO1f[0] = pack8(wa0, wa1); WO1f[1] = pack8(wa2, wa3);
      WO2f[0] = pack8(wb0, wb1); WO2f[1] = pack8(wb2, wb3);
      #pragma unroll
      for (int r = 0; r < 4; ++r)
        st2(sX, lk * 4 + r, (c2 * 16 + l15) * 2, 128, cvt1(outAcc[r]));
    } else if (more) {
      stage_lower(seB, sA, nr0, tid - 256, 16);
    }
    __syncthreads();   // bar2: X ready; staging writes done

    // ---- Phase D: head GEMM 1 (waves 0-3) ----
    if (isHead) {
      f32x4 acc = {0, 0, 0, 0};
      #pragma unroll
      for (int ks = 0; ks < 2; ++ks)
        acc = __builtin_amdgcn_mfma_f32_16x16x32_bf16(
            ldfrag(sX, l15, ks * 64 + kb0, 128), WO1f[ks], acc, 0, 0, 0);
      #pragma unroll
      for (int r = 0; r < 4; ++r)
        st2(sP, lk * 4 + r, (c2 * 16 + l15) * 2, 128, cvt1(fmaxf(acc[r] + bo1v, 0.f)));
    }
    __syncthreads();   // bar3: P ready

    // ---- Phase E: head GEMM 2 + col-sum accumulate (waves 0-3) ----
    if (isHead) {
      f32x4 acc = {0, 0, 0, 0};
      #pragma unroll
      for (int ks = 0; ks < 2; ++ks)
        acc = __builtin_amdgcn_mfma_f32_16x16x32_bf16(
            ldfrag(sP, l15, ks * 64 + kb0, 128), WO2f[ks], acc, 0, 0, 0);
      float s = 0.f;
      #pragma unroll
      for (int r = 0; r < 4; ++r) s += fmaxf(acc[r] + bo2v, 0.f);
      s += __shfl_xor(s, 16);
      s += __shfl_xor(s, 32);
      if (lk == 0) sAccC[c2 * 16 + l15] += s;
    }
    __syncthreads();   // bar4: chunk cc+1 fully staged; sAccC settled
  }

  if (tid < 64) ws[((size_t)batch * 2 + half) * 64 + tid] = sAccC[tid];
}

// 32 blocks x 512: 8 batches/block; sum 2 half-partials, mean over 256, project 64->2.
__global__ __launch_bounds__(512) void finish_kernel(
    const float* __restrict__ ws,
    const float* __restrict__ wo3, const float* __restrict__ bo3,
    float* __restrict__ out)
{
  int b = blockIdx.x * 8 + (threadIdx.x >> 6);
  int l = threadIdx.x & 63;
  float s = (ws[((size_t)b * 2 + 0) * 64 + l] + ws[((size_t)b * 2 + 1) * 64 + l]) * (1.0f / 256.0f);
  float v0 = s * wo3[l];
  float v1 = s * wo3[64 + l];
  #pragma unroll
  for (int off = 32; off > 0; off >>= 1) {
    v0 += __shfl_down(v0, off);
    v1 += __shfl_down(v1, off);
  }
  if (l == 0) {
    out[b * 2 + 0] = v0 + bo3[0];
    out[b * 2 + 1] = v1 + bo3[1];
  }
}

extern "C" void kernel_launch(void* const* d_in, const int* in_sizes, int n_in,
                              void* d_out, int out_size, void* d_ws, size_t ws_size,
                              hipStream_t stream) {
  (void)in_sizes; (void)n_in; (void)ws_size; (void)out_size;
  const float* se  = (const float*)d_in[1];   // d_in[0] = `inputs` — shape-only, never read
  const float* w1  = (const float*)d_in[2];
  const float* b1  = (const float*)d_in[3];
  const float* w2  = (const float*)d_in[4];
  const float* b2  = (const float*)d_in[5];
  const float* wo1 = (const float*)d_in[6];
  const float* bo1 = (const float*)d_in[7];
  const float* wo2 = (const float*)d_in[8];
  const float* bo2 = (const float*)d_in[9];
  const float* wo3 = (const float*)d_in[10];
  const float* bo3 = (const float*)d_in[11];
  float* ws = (float*)d_ws;                   // 512 * 64 floats = 128 KB
  chunk_kernel<<<dim3(512), dim3(512), 0, stream>>>(
      se, w1, b1, w2, b2, wo1, bo1, wo2, bo2, ws);
  finish_kernel<<<dim3(32), dim3(512), 0, stream>>>(ws, wo3, bo3, (float*)d_out);
}